// Round 2
// baseline (85.882 us; speedup 1.0000x reference)
//
#include <hip/hip_runtime.h>

// GreedyThresh decode: B=4096 rows, V=128 sequential steps, U1=129 cols.
// One wave (64 lanes) per batch row; lane l owns cols 1+l and 65+l.
// Col 0 (skip) has weight 0 always -> only selected on fallback.
// Key packing: valid candidates are in [0.5, 1.0) => biased exp 126 for all,
// so 23-bit mantissa orders values. key = (mant << 8) | (255 - col):
// max key == max value, then lowest column (matches jnp.argmax tie-break).

#define NB 4096
#define NV 128
#define NU1 129
#define WAVES_PER_BLOCK 4

__global__ __launch_bounds__(256)
void greedy_thresh_kernel(const float* __restrict__ w, float* __restrict__ out) {
    const int wave = blockIdx.x * WAVES_PER_BLOCK + (threadIdx.x >> 6);
    const int lane = threadIdx.x & 63;

    const float* __restrict__ wb = w + (size_t)wave * (NV * NU1);
    float* __restrict__ out_neg = out;            // [NB]  (-size)
    float* __restrict__ out_sel = out + NB;       // [NB*NV] (sel as float)

    const int c0 = 1 + lane;       // 1..64
    const int c1 = 65 + lane;      // 65..128
    bool m0 = false, m1 = false;   // mask bits for owned columns
    float size = 0.0f;

    // prefetch row 0
    float v0 = wb[c0];
    float v1 = wb[c1];

    for (int i = 0; i < NV; ++i) {
        // prefetch next row (overlaps with the reduction below)
        float n0 = 0.0f, n1 = 0.0f;
        if (i + 1 < NV) {
            const float* nrow = wb + (size_t)(i + 1) * NU1;
            n0 = nrow[c0];
            n1 = nrow[c1];
        }

        // build candidate keys (0 = invalid)
        unsigned k0 = 0u, k1 = 0u;
        if (!m0 && v0 >= 0.5f)
            k0 = ((__float_as_uint(v0) & 0x7FFFFFu) << 8) | (unsigned)(255 - c0);
        if (!m1 && v1 >= 0.5f)
            k1 = ((__float_as_uint(v1) & 0x7FFFFFu) << 8) | (unsigned)(255 - c1);
        unsigned k = k0 > k1 ? k0 : k1;   // c0 < c1, ties prefer lower col via key

        // wave-wide max reduce (64 lanes)
        #pragma unroll
        for (int off = 32; off > 0; off >>= 1) {
            unsigned o = __shfl_xor(k, off, 64);
            k = (o > k) ? o : k;
        }

        int sel = 0;
        if (k != 0u) {
            sel = 255 - (int)(k & 0xFFu);
            float val = __uint_as_float(0x3F000000u | (k >> 8));  // exp 126 | mant
            size += val;                  // chosen = original weight of sel
            if (sel == c0) m0 = true;
            else if (sel == c1) m1 = true;
        }
        // fallback: sel = 0, chosen = w_i[0] = 0 -> nothing to add

        if (lane == 0) out_sel[(size_t)wave * NV + i] = (float)sel;

        v0 = n0;
        v1 = n1;
    }

    if (lane == 0) out_neg[wave] = -size;
}

extern "C" void kernel_launch(void* const* d_in, const int* in_sizes, int n_in,
                              void* d_out, int out_size, void* d_ws, size_t ws_size,
                              hipStream_t stream) {
    const float* w = (const float*)d_in[0];
    float* out = (float*)d_out;
    const int blocks = NB / WAVES_PER_BLOCK;  // 1024
    greedy_thresh_kernel<<<blocks, 64 * WAVES_PER_BLOCK, 0, stream>>>(w, out);
}

// Round 3
// 54.668 us; speedup vs baseline: 1.5710x; 1.5710x over previous
//
#include <hip/hip_runtime.h>

// GreedyThresh decode: B=4096 rows, V=128 sequential steps, U1=129 cols.
// One wave per batch row; lane l owns cols 1+l and 65+l.
// Key packing: all valid candidates in [0.5,1.0) => biased exp 126, so the
// 23-bit mantissa orders values. key = (mant << 8) | (255 - col): max key ==
// max value, then lowest column (matches jnp.argmax tie-break). Verified r2.
//
// r3 change: 8-row-deep register prefetch ring (statically indexed via full
// unroll) to fix the latency-bound profile (831 GB/s, VALUBusy 19%), plus
// coalesced float2 epilogue for sels instead of per-iter lane-0 stores.

#define NB 4096
#define NV 128
#define NU1 129
#define WPB 4
#define PD 8   // prefetch depth (rows in flight per wave)

__global__ __launch_bounds__(256)
void greedy_thresh_kernel(const float* __restrict__ w, float* __restrict__ out) {
    const int wave = blockIdx.x * WPB + (threadIdx.x >> 6);
    const int lane = threadIdx.x & 63;

    const float* __restrict__ wb = w + (size_t)wave * (NV * NU1);
    float* __restrict__ out_neg = out;            // [NB]  (-size)
    float* __restrict__ out_sel = out + NB;       // [NB*NV] (sel as float)

    const int c0 = 1 + lane;       // 1..64
    const int c1 = 65 + lane;      // 65..128
    bool m0 = false, m1 = false;
    float size = 0.0f;
    float s0 = 0.0f, s1 = 0.0f;    // this lane's two sel outputs (iters 2*lane, 2*lane+1)

    float p0[PD], p1[PD];
    #pragma unroll
    for (int d = 0; d < PD; ++d) {
        p0[d] = wb[d * NU1 + c0];
        p1[d] = wb[d * NU1 + c1];
    }

#define BODY(iexpr, dd, PREFETCH)                                              \
    {                                                                          \
        const int i = (iexpr);                                                 \
        const float v0 = p0[dd], v1 = p1[dd];                                  \
        if (PREFETCH) {                                                        \
            const float* nrow = wb + (size_t)(i + PD) * NU1;                   \
            p0[dd] = nrow[c0];                                                 \
            p1[dd] = nrow[c1];                                                 \
        }                                                                      \
        unsigned k0 = 0u, k1 = 0u;                                             \
        if (!m0 && v0 >= 0.5f)                                                 \
            k0 = ((__float_as_uint(v0) & 0x7FFFFFu) << 8) | (unsigned)(255 - c0); \
        if (!m1 && v1 >= 0.5f)                                                 \
            k1 = ((__float_as_uint(v1) & 0x7FFFFFu) << 8) | (unsigned)(255 - c1); \
        unsigned k = k0 > k1 ? k0 : k1;                                        \
        _Pragma("unroll")                                                      \
        for (int off = 32; off > 0; off >>= 1) {                               \
            unsigned o = __shfl_xor(k, off, 64);                               \
            k = (o > k) ? o : k;                                               \
        }                                                                      \
        int sel = 0;                                                           \
        if (k != 0u) {                                                         \
            sel = 255 - (int)(k & 0xFFu);                                      \
            size += __uint_as_float(0x3F000000u | (k >> 8));                   \
            if (sel == c0) m0 = true;                                          \
            else if (sel == c1) m1 = true;                                     \
        }                                                                      \
        if ((i >> 1) == lane) {                                                \
            if (i & 1) s1 = (float)sel; else s0 = (float)sel;                  \
        }                                                                      \
    }

    // main loop: rows 0..NV-PD-1, prefetching rows PD..NV-1
    for (int ib = 0; ib < NV - PD; ib += PD) {
        #pragma unroll
        for (int d = 0; d < PD; ++d)
            BODY(ib + d, d, true)
    }
    // tail: last PD rows, no prefetch
    #pragma unroll
    for (int d = 0; d < PD; ++d)
        BODY(NV - PD + d, d, false)

#undef BODY

    // coalesced epilogue: lane j writes sels for iterations 2j, 2j+1
    float2 sv = make_float2(s0, s1);
    *reinterpret_cast<float2*>(&out_sel[(size_t)wave * NV + 2 * lane]) = sv;
    if (lane == 0) out_neg[wave] = -size;
}

extern "C" void kernel_launch(void* const* d_in, const int* in_sizes, int n_in,
                              void* d_out, int out_size, void* d_ws, size_t ws_size,
                              hipStream_t stream) {
    const float* w = (const float*)d_in[0];
    float* out = (float*)d_out;
    const int blocks = NB / WPB;  // 1024
    greedy_thresh_kernel<<<blocks, 64 * WPB, 0, stream>>>(w, out);
}

// Round 4
// 48.005 us; speedup vs baseline: 1.7890x; 1.1388x over previous
//
#include <hip/hip_runtime.h>

// GreedyThresh decode: B=4096 rows, V=128 sequential steps, U1=129 cols.
// One wave per batch row; lane l owns cols 1+l and 65+l.
// Key packing: all valid candidates in [0.5,1.0) => biased exp 126, so the
// 23-bit mantissa orders values. key = (mant << 8) | (255 - col): max key ==
// max value, then lowest column (matches jnp.argmax tie-break). Verified r2.
// Keys are < 2^31, so signed max == unsigned max.
//
// r4 change: wave-max via DPP (row_shr 1/2/4/8 + row_bcast 15/31 + readlane 63)
// instead of 6x __shfl_xor. Removes all LDS-pipe ds ops (~30 us of LDS-pipe
// occupancy per CU) and shortens the per-iter dependent chain; post-reduce
// tail becomes wave-uniform (SGPR) via readlane.

#define NB 4096
#define NV 128
#define NU1 129
#define WPB 4
#define PD 8   // prefetch depth (rows in flight per wave)

__device__ __forceinline__ int imax(int a, int b) { return a > b ? a : b; }

// full-wave (64-lane) max; result returned wave-uniform.
__device__ __forceinline__ unsigned wave_max64(unsigned ku) {
    int v = (int)ku, t;
    t = __builtin_amdgcn_update_dpp(0, v, 0x111, 0xf, 0xf, true); v = imax(v, t); // row_shr:1
    t = __builtin_amdgcn_update_dpp(0, v, 0x112, 0xf, 0xf, true); v = imax(v, t); // row_shr:2
    t = __builtin_amdgcn_update_dpp(0, v, 0x114, 0xf, 0xf, true); v = imax(v, t); // row_shr:4
    t = __builtin_amdgcn_update_dpp(0, v, 0x118, 0xf, 0xf, true); v = imax(v, t); // row_shr:8
    t = __builtin_amdgcn_update_dpp(0, v, 0x142, 0xf, 0xf, true); v = imax(v, t); // row_bcast:15
    t = __builtin_amdgcn_update_dpp(0, v, 0x143, 0xf, 0xf, true); v = imax(v, t); // row_bcast:31
    return (unsigned)__builtin_amdgcn_readlane(v, 63);
}

__global__ __launch_bounds__(256)
void greedy_thresh_kernel(const float* __restrict__ w, float* __restrict__ out) {
    const int wave = blockIdx.x * WPB + (threadIdx.x >> 6);
    const int lane = threadIdx.x & 63;

    const float* __restrict__ wb = w + (size_t)wave * (NV * NU1);
    float* __restrict__ out_neg = out;            // [NB]  (-size)
    float* __restrict__ out_sel = out + NB;       // [NB*NV] (sel as float)

    const int c0 = 1 + lane;       // 1..64
    const int c1 = 65 + lane;      // 65..128
    bool m0 = false, m1 = false;
    float size = 0.0f;
    float s0 = 0.0f, s1 = 0.0f;    // this lane's two sel outputs (iters 2*lane, 2*lane+1)

    float p0[PD], p1[PD];
    #pragma unroll
    for (int d = 0; d < PD; ++d) {
        p0[d] = wb[d * NU1 + c0];
        p1[d] = wb[d * NU1 + c1];
    }

#define BODY(iexpr, dd, PREFETCH)                                              \
    {                                                                          \
        const int i = (iexpr);                                                 \
        const float v0 = p0[dd], v1 = p1[dd];                                  \
        if (PREFETCH) {                                                        \
            const float* nrow = wb + (size_t)(i + PD) * NU1;                   \
            p0[dd] = nrow[c0];                                                 \
            p1[dd] = nrow[c1];                                                 \
        }                                                                      \
        unsigned k0 = 0u, k1 = 0u;                                             \
        if (!m0 && v0 >= 0.5f)                                                 \
            k0 = ((__float_as_uint(v0) & 0x7FFFFFu) << 8) | (unsigned)(255 - c0); \
        if (!m1 && v1 >= 0.5f)                                                 \
            k1 = ((__float_as_uint(v1) & 0x7FFFFFu) << 8) | (unsigned)(255 - c1); \
        const unsigned kk = wave_max64(k0 > k1 ? k0 : k1);                     \
        int sel = 0;                                                           \
        if (kk != 0u) {   /* wave-uniform branch (SGPR) */                     \
            sel = 255 - (int)(kk & 0xFFu);                                     \
            size += __uint_as_float(0x3F000000u | (kk >> 8));                  \
            m0 |= (sel == c0);                                                 \
            m1 |= (sel == c1);                                                 \
        }                                                                      \
        if ((i >> 1) == lane) {                                                \
            if (i & 1) s1 = (float)sel; else s0 = (float)sel;                  \
        }                                                                      \
    }

    // main loop: rows 0..NV-PD-1, prefetching rows PD..NV-1
    for (int ib = 0; ib < NV - PD; ib += PD) {
        #pragma unroll
        for (int d = 0; d < PD; ++d)
            BODY(ib + d, d, true)
    }
    // tail: last PD rows, no prefetch
    #pragma unroll
    for (int d = 0; d < PD; ++d)
        BODY(NV - PD + d, d, false)

#undef BODY

    // coalesced epilogue: lane j writes sels for iterations 2j, 2j+1
    float2 sv = make_float2(s0, s1);
    *reinterpret_cast<float2*>(&out_sel[(size_t)wave * NV + 2 * lane]) = sv;
    if (lane == 0) out_neg[wave] = -size;
}

extern "C" void kernel_launch(void* const* d_in, const int* in_sizes, int n_in,
                              void* d_out, int out_size, void* d_ws, size_t ws_size,
                              hipStream_t stream) {
    const float* w = (const float*)d_in[0];
    float* out = (float*)d_out;
    const int blocks = NB / WPB;  // 1024
    greedy_thresh_kernel<<<blocks, 64 * WPB, 0, stream>>>(w, out);
}

// Round 6
// 47.842 us; speedup vs baseline: 1.7951x; 1.0034x over previous
//
#include <hip/hip_runtime.h>

// GreedyThresh decode: B=4096 rows, V=128 sequential steps, U1=129 cols.
// One wave per batch row; lane l owns cols 1+l and 65+l.
// Key packing: all valid candidates in [0.5,1.0) => biased exp 126, so the
// 23-bit mantissa orders values. key = (mant << 8) | (255 - col): max key ==
// max value, then lowest column (matches jnp.argmax tie-break). Verified r2.
// Keys < 2^31, so signed max == unsigned max.
//
// r5: chain-latency attack.
//  - fused v_max_i32_dpp reduce (6 dep ops instead of 12); s_nop 1 embedded
//    in each asm stmt covers VALU-write -> DPP-read hazards the compiler
//    can't see inside inline asm.
//  - key-build software-pipelined one iteration ahead (depends only on loads,
//    not on the mask); mask enters via one v_and with keep0/keep1 (0 / ~0).
//  - branchless scalar tail (s_cselect, no per-iter s_cbranch).

#define NB 4096
#define NV 128
#define NU1 129
#define WPB 4
#define PD 8   // prefetch depth (rows in flight per wave), power of 2

__device__ __forceinline__ unsigned mkkey(float v, unsigned inv) {
    unsigned k = ((__float_as_uint(v) & 0x7FFFFFu) << 8) | inv;
    return v >= 0.5f ? k : 0u;
}

// RMW max with DPP on src0: x = max(dpp(x), x). bound_ctrl off => lanes with
// invalid source keep their old value (equivalent to skipping the max).
#define DPPMAX(x, ctl)                                                         \
    asm("s_nop 1\n\tv_max_i32_dpp %0, %0, %0 " ctl                             \
        " row_mask:0xf bank_mask:0xf"                                          \
        : "+v"(x))

__global__ __launch_bounds__(256)
void greedy_thresh_kernel(const float* __restrict__ w, float* __restrict__ out) {
    const int wave = blockIdx.x * WPB + (threadIdx.x >> 6);
    const int lane = threadIdx.x & 63;

    const float* __restrict__ wb = w + (size_t)wave * (NV * NU1);
    float* __restrict__ out_neg = out;            // [NB]  (-size)
    float* __restrict__ out_sel = out + NB;       // [NB*NV] (sel as float)

    const int c0 = 1 + lane;            // 1..64
    const int c1 = 65 + lane;           // 65..128
    const unsigned inv0 = 255 - c0;
    const unsigned inv1 = 255 - c1;
    unsigned keep0 = ~0u, keep1 = ~0u;  // 0 once this lane's column is masked
    float size = 0.0f;
    float s0 = 0.0f, s1 = 0.0f;         // this lane's sel outputs (iters 2l, 2l+1)

    float p0[PD], p1[PD];               // float ring, PD rows in flight
    #pragma unroll
    for (int d = 0; d < PD; ++d) {
        p0[d] = wb[d * NU1 + c0];
        p1[d] = wb[d * NU1 + c1];
    }
    // raw keys for row 0 (mask-independent)
    unsigned kr0 = mkkey(p0[0], inv0);
    unsigned kr1 = mkkey(p1[0], inv1);

#define BODY(iexpr, dd, PREF, BLD)                                             \
    {                                                                          \
        const int i = (iexpr);                                                 \
        /* chain: keep -> and -> max */                                        \
        unsigned ka = kr0 & keep0;                                             \
        unsigned kb = kr1 & keep1;                                             \
        int v = (int)(ka > kb ? ka : kb);                                      \
        /* off-chain: prefetch row i+PD into slot dd */                        \
        if (PREF) {                                                            \
            const float* nrow = wb + (size_t)(i + PD) * NU1;                   \
            p0[dd] = nrow[c0];                                                 \
            p1[dd] = nrow[c1];                                                 \
        }                                                                      \
        /* off-chain: build raw keys for row i+1 */                            \
        if (BLD) {                                                             \
            kr0 = mkkey(p0[(dd + 1) & (PD - 1)], inv0);                        \
            kr1 = mkkey(p1[(dd + 1) & (PD - 1)], inv1);                        \
        }                                                                      \
        /* fused DPP max reduce, result uniform in lane 63 */                  \
        DPPMAX(v, "row_shr:1");                                                \
        DPPMAX(v, "row_shr:2");                                                \
        DPPMAX(v, "row_shr:4");                                                \
        DPPMAX(v, "row_shr:8");                                                \
        DPPMAX(v, "row_bcast:15");                                             \
        DPPMAX(v, "row_bcast:31");                                             \
        unsigned kk;                                                           \
        asm("s_nop 1\n\tv_readlane_b32 %0, %1, 63" : "=s"(kk) : "v"(v));       \
        /* branchless scalar tail */                                           \
        const int sel = kk ? (255 - (int)(kk & 0xFFu)) : 0;                    \
        size += __uint_as_float(kk ? (0x3F000000u | (kk >> 8)) : 0u);          \
        keep0 = (sel == c0) ? 0u : keep0;                                      \
        keep1 = (sel == c1) ? 0u : keep1;                                      \
        const float self = (float)sel;                                         \
        if ((i >> 1) == lane) { if (i & 1) s1 = self; else s0 = self; }        \
    }

    // main: 15 blocks with prefetch; tail block without
    for (int ib = 0; ib < NV - PD; ib += PD) {
        #pragma unroll
        for (int d = 0; d < PD; ++d)
            BODY(ib + d, d, true, true)
    }
    #pragma unroll
    for (int d = 0; d < PD; ++d)
        BODY(NV - PD + d, d, false, (d < PD - 1))

#undef BODY

    // coalesced epilogue: lane j writes sels for iterations 2j, 2j+1
    float2 sv = make_float2(s0, s1);
    *reinterpret_cast<float2*>(&out_sel[(size_t)wave * NV + 2 * lane]) = sv;
    if (lane == 0) out_neg[wave] = -size;
}

extern "C" void kernel_launch(void* const* d_in, const int* in_sizes, int n_in,
                              void* d_out, int out_size, void* d_ws, size_t ws_size,
                              hipStream_t stream) {
    const float* w = (const float*)d_in[0];
    float* out = (float*)d_out;
    const int blocks = NB / WPB;  // 1024
    greedy_thresh_kernel<<<blocks, 64 * WPB, 0, stream>>>(w, out);
}